// Round 4
// baseline (163.461 us; speedup 1.0000x reference)
//
#include <hip/hip_runtime.h>

#define N_PTS 200000
#define C_IN  32
#define C_OUT 64
#define K_NB  27
#define BN_EPS 1e-5f
#define NBLK  3125     // conv grid: 64 points per block

using bf16x8 = __attribute__((ext_vector_type(8))) short;
using f32x4  = __attribute__((ext_vector_type(4))) float;

// ---------------- ws layout (MFMA path) ----------------
//  [0, 114688)        wt : bf16[28][64][32]
//  [114688, 115200)   ab : float[128]
//  [115200, 1715200)  ps : float[3125][128]  (per-block partial BN sums)
//  [1835008, +12.8MB) xt : bf16[N+1][32]     (row N = zeros)
//  [14635072, +21.6MB) nt: int32[27][N]      (invalid -> N)
#define M_WT_OFF  0
#define M_AB_OFF  114688
#define M_PS_OFF  115200
#define M_XT_OFF  1835008
#define M_NT_OFF  (1835008 + 12800064)
#define M_WS_NEED ((size_t)M_NT_OFF + 27ull * N_PTS * 4ull)

// ---------------- ws layout (fallback f32 path) ----------------
#define F_WTK_OFF 0
#define F_AB_OFF  221184
#define F_Z_OFF   221696
#define F_PS_OFF  221824

__device__ __forceinline__ unsigned short f2bf(float f) {
    unsigned int u = __float_as_uint(f);
    u = (u + 0x7fffu + ((u >> 16) & 1u)) >> 16;
    return (unsigned short)u;
}

// ---------- prep: w[o][c][k] -> wt[k][o][c] bf16, k=27 zeros ----------
__global__ void k_prep_w(const float* __restrict__ w, unsigned short* __restrict__ wt) {
    int i = blockIdx.x * 256 + threadIdx.x;
    if (i >= 28 * C_OUT * C_IN) return;
    int c = i & 31, o = (i >> 5) & 63, k = i >> 11;
    wt[i] = (k < K_NB) ? f2bf(w[(o * C_IN + c) * K_NB + k]) : (unsigned short)0;
}

// ---------- prep: x -> xt (bf16, transposed, zero row) + neigh -> nt ----------
__global__ void k_prep_xn(const float* __restrict__ x, const int* __restrict__ neigh,
                          unsigned short* __restrict__ xt, int* __restrict__ nt) {
    int n = blockIdx.x * 256 + threadIdx.x;
    if (n > N_PTS) return;
    unsigned short row[C_IN];
    if (n == N_PTS) {
#pragma unroll
        for (int c = 0; c < C_IN; ++c) row[c] = 0;
    } else {
#pragma unroll
        for (int c = 0; c < C_IN; ++c) row[c] = f2bf(x[(long long)c * N_PTS + n]);
    }
    uint4* dst = (uint4*)(xt + (long long)n * C_IN);
#pragma unroll
    for (int q = 0; q < 4; ++q) dst[q] = ((const uint4*)row)[q];

    if (n < N_PTS) {
#pragma unroll
        for (int k = 0; k < K_NB; ++k) {
            int t = neigh[n * K_NB + k];
            nt[k * N_PTS + n] = (t >= 0 && t < N_PTS) ? t : N_PTS;
        }
    }
}

// ---------- conv via MFMA, 16 pts/wave, 2-deep gather prefetch, fused BN partials ----------
__launch_bounds__(256, 6)
__global__ void k_conv_mfma(const unsigned short* __restrict__ xt,
                            const int* __restrict__ nt,
                            const unsigned short* __restrict__ wt,
                            float* __restrict__ out,
                            float* __restrict__ ps) {
    __shared__ float sred[512];
    const int lane = threadIdx.x & 63;
    const int wv   = threadIdx.x >> 6;
    const int n0   = blockIdx.x * 64 + wv * 16;
    const int l15  = lane & 15, lq = lane >> 4;

    const unsigned short* xt_q = xt + lq * 8;               // + t*32
    const unsigned short* wt_q = wt + l15 * C_IN + lq * 8;  // + k*2048 + ot*512
    const int nb = n0 + l15;

    f32x4 acc[4];
#pragma unroll
    for (int ot = 0; ot < 4; ++ot) acc[ot] = f32x4{0.f, 0.f, 0.f, 0.f};

    int t2;
    bf16x8 B0, B1;
    {
        int t0 = nt[nb];
        int t1 = nt[N_PTS + nb];
        t2     = nt[2 * N_PTS + nb];
        B0 = *(const bf16x8*)(xt_q + (long long)t0 * C_IN);
        B1 = *(const bf16x8*)(xt_q + (long long)t1 * C_IN);
    }

    for (int k = 0; k < K_NB; ++k) {
        bf16x8 B2 = *(const bf16x8*)(xt_q + (long long)t2 * C_IN);   // for k+2
        int krow = k + 3; if (krow > K_NB - 1) krow = K_NB - 1;      // clamped prefetch
        int t3 = nt[krow * N_PTS + nb];
        bf16x8 A[4];
#pragma unroll
        for (int ot = 0; ot < 4; ++ot)
            A[ot] = *(const bf16x8*)(wt_q + k * 2048 + ot * 512);
#pragma unroll
        for (int ot = 0; ot < 4; ++ot)
            acc[ot] = __builtin_amdgcn_mfma_f32_16x16x32_bf16(A[ot], B0, acc[ot], 0, 0, 0);
        B0 = B1; B1 = B2; t2 = t3;
    }

    // raw f32 out: D layout col=l15 (point), row=lq*4+r (channel within 16-tile)
#pragma unroll
    for (int ot = 0; ot < 4; ++ot)
#pragma unroll
        for (int r = 0; r < 4; ++r)
            out[(ot * 16 + lq * 4 + r) * N_PTS + nb] = acc[ot][r];

    // fused BN partials: reduce sum / sumsq over the 16 points (low-4 lane bits)
    f32x4 sq[4];
#pragma unroll
    for (int ot = 0; ot < 4; ++ot) sq[ot] = acc[ot] * acc[ot];
#pragma unroll
    for (int d = 1; d < 16; d <<= 1) {
#pragma unroll
        for (int ot = 0; ot < 4; ++ot)
#pragma unroll
            for (int r = 0; r < 4; ++r) {
                acc[ot][r] += __shfl_xor(acc[ot][r], d);
                sq[ot][r]  += __shfl_xor(sq[ot][r], d);
            }
    }
    if (l15 == 0) {
#pragma unroll
        for (int ot = 0; ot < 4; ++ot)
#pragma unroll
            for (int r = 0; r < 4; ++r) {
                int ch = ot * 16 + lq * 4 + r;
                sred[wv * 128 + ch]      = acc[ot][r];
                sred[wv * 128 + 64 + ch] = sq[ot][r];
            }
    }
    __syncthreads();
    if (threadIdx.x < 128) {
        float v = sred[threadIdx.x] + sred[128 + threadIdx.x] +
                  sred[256 + threadIdx.x] + sred[384 + threadIdx.x];
        ps[blockIdx.x * 128 + threadIdx.x] = v;
    }
}

// ---------- reduce per-block partials -> a,b ----------
__global__ void k_stats2(const float* __restrict__ ps, const float* __restrict__ gamma,
                         const float* __restrict__ beta, float* __restrict__ ab) {
    int ch = blockIdx.x;   // 64 blocks
    float s = 0.f, s2 = 0.f;
    for (int b = threadIdx.x; b < NBLK; b += 256) {
        s  += ps[b * 128 + ch];
        s2 += ps[b * 128 + 64 + ch];
    }
#pragma unroll
    for (int off = 32; off > 0; off >>= 1) {
        s  += __shfl_down(s, off, 64);
        s2 += __shfl_down(s2, off, 64);
    }
    __shared__ float r0[4], r1[4];
    int wv = threadIdx.x >> 6;
    if ((threadIdx.x & 63) == 0) { r0[wv] = s; r1[wv] = s2; }
    __syncthreads();
    if (threadIdx.x == 0) {
        float S = r0[0] + r0[1] + r0[2] + r0[3];
        float S2 = r1[0] + r1[1] + r1[2] + r1[3];
        float mean = S / (float)N_PTS;
        float var  = S2 / (float)N_PTS - mean * mean;
        float a = gamma[ch] * rsqrtf(var + BN_EPS);
        float b = beta[ch] - mean * a;
        ab[ch]      = a;
        ab[64 + ch] = b;
    }
}

// ---------- normalize + relu, in place on d_out ----------
__global__ void k_norm(float* __restrict__ out, const float* __restrict__ ab) {
    int i = blockIdx.x * 256 + threadIdx.x;
    const int total4 = (C_OUT * N_PTS) / 4;
    if (i >= total4) return;
    int o = (i * 4) / N_PTS;
    float a = ab[o], b = ab[64 + o];
    float4 v = ((float4*)out)[i];
    v.x = fmaxf(fmaf(v.x, a, b), 0.f);
    v.y = fmaxf(fmaf(v.y, a, b), 0.f);
    v.z = fmaxf(fmaf(v.z, a, b), 0.f);
    v.w = fmaxf(fmaf(v.w, a, b), 0.f);
    ((float4*)out)[i] = v;
}

// ================= fallback f32 path (small ws) =================
__global__ void k_wt_f32(const float* __restrict__ w, float* __restrict__ wtk) {
    int i = blockIdx.x * 256 + threadIdx.x;
    if (i >= K_NB * C_IN * C_OUT) return;
    int o = i & 63, r = i >> 6, c = r & 31, k = r >> 5;
    wtk[i] = w[(o * C_IN + c) * K_NB + k];
}

__launch_bounds__(256, 1)
__global__ void k_conv_f32(const float* __restrict__ src, const int* __restrict__ neigh,
                           const float* __restrict__ wtk, float* __restrict__ out) {
    __shared__ float wt_s[C_IN * C_OUT];
    const int lane = threadIdx.x & 63;
    const int wave = threadIdx.x >> 6;
    const int n0   = blockIdx.x * 64 + wave * 16;
    float acc[16];
#pragma unroll
    for (int p = 0; p < 16; ++p) acc[p] = 0.f;
    for (int k = 0; k < K_NB; ++k) {
        __syncthreads();
#pragma unroll
        for (int j = 0; j < 8; ++j)
            wt_s[threadIdx.x + j * 256] = wtk[k * (C_IN * C_OUT) + threadIdx.x + j * 256];
        __syncthreads();
        int t[16];
#pragma unroll
        for (int p = 0; p < 16; ++p) t[p] = neigh[(n0 + p) * K_NB + k];
#pragma unroll
        for (int c = 0; c < C_IN; ++c) {
            float wv = wt_s[c * C_OUT + lane];
#pragma unroll
            for (int p = 0; p < 16; ++p) {
                float xv = (t[p] >= 0) ? src[(long long)c * N_PTS + t[p]] : 0.f;
                acc[p] = fmaf(wv, xv, acc[p]);
            }
        }
    }
    float4* dst = (float4*)(out + (long long)lane * N_PTS + n0);
#pragma unroll
    for (int q = 0; q < 4; ++q) dst[q] = ((const float4*)acc)[q];
}

__global__ void k_stats1(const float* __restrict__ raw, float* __restrict__ ps) {
    int o = blockIdx.x & 63, sl = blockIdx.x >> 6;
    const int per = N_PTS / 8;
    const float4* row = (const float4*)(raw + (long long)o * N_PTS + (long long)sl * per);
    float s = 0.f, s2 = 0.f;
    for (int i = threadIdx.x; i < per / 4; i += 256) {
        float4 v = row[i];
        s  += v.x + v.y + v.z + v.w;
        s2 += v.x * v.x + v.y * v.y + v.z * v.z + v.w * v.w;
    }
#pragma unroll
    for (int off = 32; off > 0; off >>= 1) {
        s  += __shfl_down(s, off, 64);
        s2 += __shfl_down(s2, off, 64);
    }
    __shared__ float r0[4], r1[4];
    int wv = threadIdx.x >> 6;
    if ((threadIdx.x & 63) == 0) { r0[wv] = s; r1[wv] = s2; }
    __syncthreads();
    if (threadIdx.x == 0) {
        ps[blockIdx.x]       = r0[0] + r0[1] + r0[2] + r0[3];
        ps[512 + blockIdx.x] = r1[0] + r1[1] + r1[2] + r1[3];
    }
}

__global__ void k_stats2f(const float* __restrict__ ps, const float* __restrict__ gamma,
                          const float* __restrict__ beta, float* __restrict__ ab) {
    int o = threadIdx.x;
    float S = 0.f, S2 = 0.f;
#pragma unroll
    for (int sl = 0; sl < 8; ++sl) {
        S  += ps[sl * 64 + o];
        S2 += ps[512 + sl * 64 + o];
    }
    float mean = S / (float)N_PTS;
    float var  = S2 / (float)N_PTS - mean * mean;
    float a = gamma[o] * rsqrtf(var + BN_EPS);
    float b = beta[o] - mean * a;
    ab[o]      = a;
    ab[64 + o] = b;
}

extern "C" void kernel_launch(void* const* d_in, const int* in_sizes, int n_in,
                              void* d_out, int out_size, void* d_ws, size_t ws_size,
                              hipStream_t stream) {
    const float* x   = (const float*)d_in[0];
    const int*   nb  = (const int*)d_in[1];     // int64 in ref -> int32 on device
    const float* w   = (const float*)d_in[2];
    const float* gam = (const float*)d_in[3];
    const float* bet = (const float*)d_in[4];
    float* out = (float*)d_out;
    char* ws = (char*)d_ws;

    if (ws_size >= M_WS_NEED) {
        unsigned short* wt = (unsigned short*)(ws + M_WT_OFF);
        float*          ab = (float*)(ws + M_AB_OFF);
        float*          ps = (float*)(ws + M_PS_OFF);
        unsigned short* xt = (unsigned short*)(ws + M_XT_OFF);
        int*            nt = (int*)(ws + M_NT_OFF);

        k_prep_w<<<(28 * C_OUT * C_IN + 255) / 256, 256, 0, stream>>>(w, wt);
        k_prep_xn<<<(N_PTS + 256) / 256, 256, 0, stream>>>(x, nb, xt, nt);
        k_conv_mfma<<<NBLK, 256, 0, stream>>>(xt, nt, wt, out, ps);
        k_stats2<<<C_OUT, 256, 0, stream>>>(ps, gam, bet, ab);
        k_norm<<<((C_OUT * N_PTS) / 4 + 255) / 256, 256, 0, stream>>>(out, ab);
    } else {
        float* wtk  = (float*)(ws + F_WTK_OFF);
        float* ab   = (float*)(ws + F_AB_OFF);
        float* ps   = (float*)(ws + F_PS_OFF);
        k_wt_f32<<<(K_NB * C_IN * C_OUT + 255) / 256, 256, 0, stream>>>(w, wtk);
        k_conv_f32<<<N_PTS / 64, 256, 0, stream>>>(x, nb, wtk, out);
        k_stats1<<<512, 256, 0, stream>>>(out, ps);
        k_stats2f<<<1, 64, 0, stream>>>(ps, gam, bet, ab);
        k_norm<<<((C_OUT * N_PTS) / 4 + 255) / 256, 256, 0, stream>>>(out, ab);
    }
}

// Round 5
// 134.392 us; speedup vs baseline: 1.2163x; 1.2163x over previous
//
#include <hip/hip_runtime.h>

#define N_PTS 200000
#define C_IN  32
#define C_OUT 64
#define K_NB  27
#define BN_EPS 1e-5f
#define CBLK  1563     // conv grid: 128 points per block (32 per wave)

using bf16x8 = __attribute__((ext_vector_type(8))) short;
using f32x4  = __attribute__((ext_vector_type(4))) float;

// ---------------- ws layout (MFMA path) ----------------
//  [0, 114688)          wt : bf16[28][64][32]   (row 27 zeros)
//  [114688, 115200)     ab : float[128]
//  [115200, 915456)     ps : float[1563][128]   (per-block partial BN sums)
//  [1048576, +12.8MB)   xt : bf16[N+1][32]      (row N = zeros)
//  [13848640, +22.4MB)  nt : int32[28][N]       (invalid -> N; row 27 = N)
#define M_WT_OFF  0
#define M_AB_OFF  114688
#define M_PS_OFF  115200
#define M_XT_OFF  1048576
#define M_NT_OFF  (1048576 + 12800064)
#define M_WS_NEED ((size_t)M_NT_OFF + 28ull * N_PTS * 4ull)

// ---------------- ws layout (fallback f32 path) ----------------
#define F_WTK_OFF 0
#define F_AB_OFF  221184
#define F_PS_OFF  221824

__device__ __forceinline__ unsigned short f2bf(float f) {
    unsigned int u = __float_as_uint(f);
    u = (u + 0x7fffu + ((u >> 16) & 1u)) >> 16;
    return (unsigned short)u;
}

// ---------- fused prep: blocks [0,782): x->xt bf16 + neigh->nt ; [782,1006): w->wt ----------
__global__ void k_prep(const float* __restrict__ x, const int* __restrict__ neigh,
                       const float* __restrict__ w,
                       unsigned short* __restrict__ xt, int* __restrict__ nt,
                       unsigned short* __restrict__ wt) {
    if (blockIdx.x < 782) {
        int n = blockIdx.x * 256 + threadIdx.x;
        if (n > N_PTS) return;
        unsigned short row[C_IN];
        if (n == N_PTS) {
#pragma unroll
            for (int c = 0; c < C_IN; ++c) row[c] = 0;
        } else {
#pragma unroll
            for (int c = 0; c < C_IN; ++c) row[c] = f2bf(x[(long long)c * N_PTS + n]);
        }
        uint4* dst = (uint4*)(xt + (long long)n * C_IN);
#pragma unroll
        for (int q = 0; q < 4; ++q) dst[q] = ((const uint4*)row)[q];

        if (n < N_PTS) {
#pragma unroll
            for (int k = 0; k < K_NB; ++k) {
                int t = neigh[n * K_NB + k];
                nt[k * N_PTS + n] = (t >= 0 && t < N_PTS) ? t : N_PTS;
            }
            nt[27 * N_PTS + n] = N_PTS;   // pad row for clamped prefetch
        }
    } else {
        int i = (blockIdx.x - 782) * 256 + threadIdx.x;
        if (i >= 28 * C_OUT * C_IN) return;
        int c = i & 31, o = (i >> 5) & 63, k = i >> 11;
        wt[i] = (k < K_NB) ? f2bf(w[(o * C_IN + c) * K_NB + k]) : (unsigned short)0;
    }
}

// ---------- conv via MFMA: 32 pts/wave, A 1-deep + B 2-deep prefetch, fused BN partials ----------
__launch_bounds__(256, 5)
__global__ void k_conv_mfma(const unsigned short* __restrict__ xt,
                            const int* __restrict__ nt,
                            const unsigned short* __restrict__ wt,
                            float* __restrict__ out,
                            float* __restrict__ ps) {
    __shared__ float sred[512];
    const int lane = threadIdx.x & 63;
    const int wv   = threadIdx.x >> 6;
    const int n0   = blockIdx.x * 128 + wv * 32;
    const int l15  = lane & 15, lq = lane >> 4;
    const bool active = (n0 < N_PTS);

    if (active) {
        const unsigned short* xt_q = xt + lq * 8;               // + t*32
        const unsigned short* wt_q = wt + l15 * C_IN + lq * 8;  // + k*2048 + ot*512
        const int nb = n0 + l15;

        f32x4 acc[2][4];
#pragma unroll
        for (int g = 0; g < 2; ++g)
#pragma unroll
            for (int ot = 0; ot < 4; ++ot) acc[g][ot] = f32x4{0.f, 0.f, 0.f, 0.f};

        int tA[2], tB[2];
        bf16x8 B0[2], B1[2], An[4];
        {
            int r0[2], r1[2];
#pragma unroll
            for (int g = 0; g < 2; ++g) {
                r0[g] = nt[0 * N_PTS + nb + 16 * g];
                r1[g] = nt[1 * N_PTS + nb + 16 * g];
                tA[g] = nt[2 * N_PTS + nb + 16 * g];
                tB[g] = nt[3 * N_PTS + nb + 16 * g];
            }
#pragma unroll
            for (int g = 0; g < 2; ++g) {
                B0[g] = *(const bf16x8*)(xt_q + (long long)r0[g] * C_IN);
                B1[g] = *(const bf16x8*)(xt_q + (long long)r1[g] * C_IN);
            }
#pragma unroll
            for (int ot = 0; ot < 4; ++ot)
                An[ot] = *(const bf16x8*)(wt_q + ot * 512);
        }

        for (int k = 0; k < K_NB; ++k) {
            bf16x8 Ac[4];
#pragma unroll
            for (int ot = 0; ot < 4; ++ot) Ac[ot] = An[ot];
            // issue next-iter A FIRST so waiting on A never drains the gathers
#pragma unroll
            for (int ot = 0; ot < 4; ++ot)
                An[ot] = *(const bf16x8*)(wt_q + (k + 1) * 2048 + ot * 512);  // row 27 = zeros
            // B gather for k+2
            bf16x8 Bn[2];
#pragma unroll
            for (int g = 0; g < 2; ++g)
                Bn[g] = *(const bf16x8*)(xt_q + (long long)tA[g] * C_IN);
            // neighbor indices for k+4 (clamped to pad row 27)
            int krow = k + 4; if (krow > 27) krow = 27;
            int tN[2];
#pragma unroll
            for (int g = 0; g < 2; ++g) tN[g] = nt[krow * N_PTS + nb + 16 * g];

#pragma unroll
            for (int g = 0; g < 2; ++g)
#pragma unroll
                for (int ot = 0; ot < 4; ++ot)
                    acc[g][ot] = __builtin_amdgcn_mfma_f32_16x16x32_bf16(Ac[ot], B0[g], acc[g][ot], 0, 0, 0);

#pragma unroll
            for (int g = 0; g < 2; ++g) {
                B0[g] = B1[g]; B1[g] = Bn[g];
                tA[g] = tB[g]; tB[g] = tN[g];
            }
        }

        // raw f32 out: D layout col=l15 (point), row=lq*4+r (channel within 16-tile)
#pragma unroll
        for (int ot = 0; ot < 4; ++ot)
#pragma unroll
            for (int r = 0; r < 4; ++r)
#pragma unroll
                for (int g = 0; g < 2; ++g)
                    out[(ot * 16 + lq * 4 + r) * N_PTS + n0 + 16 * g + l15] = acc[g][ot][r];

        // fused BN partials over this wave's 32 points
        f32x4 s[4], sq[4];
#pragma unroll
        for (int ot = 0; ot < 4; ++ot) {
            s[ot]  = acc[0][ot] + acc[1][ot];
            sq[ot] = acc[0][ot] * acc[0][ot] + acc[1][ot] * acc[1][ot];
        }
#pragma unroll
        for (int d = 1; d < 16; d <<= 1) {
#pragma unroll
            for (int ot = 0; ot < 4; ++ot)
#pragma unroll
                for (int r = 0; r < 4; ++r) {
                    s[ot][r]  += __shfl_xor(s[ot][r], d);
                    sq[ot][r] += __shfl_xor(sq[ot][r], d);
                }
        }
        if (l15 == 0) {
#pragma unroll
            for (int ot = 0; ot < 4; ++ot)
#pragma unroll
                for (int r = 0; r < 4; ++r) {
                    int ch = ot * 16 + lq * 4 + r;
                    sred[wv * 128 + ch]      = s[ot][r];
                    sred[wv * 128 + 64 + ch] = sq[ot][r];
                }
        }
    } else {
        if (l15 == 0) {
#pragma unroll
            for (int ot = 0; ot < 4; ++ot)
#pragma unroll
                for (int r = 0; r < 4; ++r) {
                    int ch = ot * 16 + lq * 4 + r;
                    sred[wv * 128 + ch]      = 0.f;
                    sred[wv * 128 + 64 + ch] = 0.f;
                }
        }
    }
    __syncthreads();
    if (threadIdx.x < 128) {
        float v = sred[threadIdx.x] + sred[128 + threadIdx.x] +
                  sred[256 + threadIdx.x] + sred[384 + threadIdx.x];
        ps[blockIdx.x * 128 + threadIdx.x] = v;
    }
}

// ---------- reduce per-block partials -> a,b ----------
__global__ void k_stats2(const float* __restrict__ ps, const float* __restrict__ gamma,
                         const float* __restrict__ beta, float* __restrict__ ab) {
    int ch = blockIdx.x;   // 64 blocks
    float s = 0.f, s2 = 0.f;
    for (int b = threadIdx.x; b < CBLK; b += 256) {
        s  += ps[b * 128 + ch];
        s2 += ps[b * 128 + 64 + ch];
    }
#pragma unroll
    for (int off = 32; off > 0; off >>= 1) {
        s  += __shfl_down(s, off, 64);
        s2 += __shfl_down(s2, off, 64);
    }
    __shared__ float r0[4], r1[4];
    int wv = threadIdx.x >> 6;
    if ((threadIdx.x & 63) == 0) { r0[wv] = s; r1[wv] = s2; }
    __syncthreads();
    if (threadIdx.x == 0) {
        float S  = r0[0] + r0[1] + r0[2] + r0[3];
        float S2 = r1[0] + r1[1] + r1[2] + r1[3];
        float mean = S / (float)N_PTS;
        float var  = S2 / (float)N_PTS - mean * mean;
        float a = gamma[ch] * rsqrtf(var + BN_EPS);
        float b = beta[ch] - mean * a;
        ab[ch]      = a;
        ab[64 + ch] = b;
    }
}

// ---------- normalize + relu, in place on d_out ----------
__global__ void k_norm(float* __restrict__ out, const float* __restrict__ ab) {
    int i = blockIdx.x * 256 + threadIdx.x;
    const int total4 = (C_OUT * N_PTS) / 4;
    if (i >= total4) return;
    int o = (i * 4) / N_PTS;
    float a = ab[o], b = ab[64 + o];
    float4 v = ((float4*)out)[i];
    v.x = fmaxf(fmaf(v.x, a, b), 0.f);
    v.y = fmaxf(fmaf(v.y, a, b), 0.f);
    v.z = fmaxf(fmaf(v.z, a, b), 0.f);
    v.w = fmaxf(fmaf(v.w, a, b), 0.f);
    ((float4*)out)[i] = v;
}

// ================= fallback f32 path (small ws) =================
__global__ void k_wt_f32(const float* __restrict__ w, float* __restrict__ wtk) {
    int i = blockIdx.x * 256 + threadIdx.x;
    if (i >= K_NB * C_IN * C_OUT) return;
    int o = i & 63, r = i >> 6, c = r & 31, k = r >> 5;
    wtk[i] = w[(o * C_IN + c) * K_NB + k];
}

__launch_bounds__(256, 1)
__global__ void k_conv_f32(const float* __restrict__ src, const int* __restrict__ neigh,
                           const float* __restrict__ wtk, float* __restrict__ out) {
    __shared__ float wt_s[C_IN * C_OUT];
    const int lane = threadIdx.x & 63;
    const int wave = threadIdx.x >> 6;
    const int n0   = blockIdx.x * 64 + wave * 16;
    float acc[16];
#pragma unroll
    for (int p = 0; p < 16; ++p) acc[p] = 0.f;
    for (int k = 0; k < K_NB; ++k) {
        __syncthreads();
#pragma unroll
        for (int j = 0; j < 8; ++j)
            wt_s[threadIdx.x + j * 256] = wtk[k * (C_IN * C_OUT) + threadIdx.x + j * 256];
        __syncthreads();
        int t[16];
#pragma unroll
        for (int p = 0; p < 16; ++p) t[p] = neigh[(n0 + p) * K_NB + k];
#pragma unroll
        for (int c = 0; c < C_IN; ++c) {
            float wv = wt_s[c * C_OUT + lane];
#pragma unroll
            for (int p = 0; p < 16; ++p) {
                float xv = (t[p] >= 0) ? src[(long long)c * N_PTS + t[p]] : 0.f;
                acc[p] = fmaf(wv, xv, acc[p]);
            }
        }
    }
    float4* dst = (float4*)(out + (long long)lane * N_PTS + n0);
#pragma unroll
    for (int q = 0; q < 4; ++q) dst[q] = ((const float4*)acc)[q];
}

__global__ void k_stats1(const float* __restrict__ raw, float* __restrict__ ps) {
    int o = blockIdx.x & 63, sl = blockIdx.x >> 6;
    const int per = N_PTS / 8;
    const float4* row = (const float4*)(raw + (long long)o * N_PTS + (long long)sl * per);
    float s = 0.f, s2 = 0.f;
    for (int i = threadIdx.x; i < per / 4; i += 256) {
        float4 v = row[i];
        s  += v.x + v.y + v.z + v.w;
        s2 += v.x * v.x + v.y * v.y + v.z * v.z + v.w * v.w;
    }
#pragma unroll
    for (int off = 32; off > 0; off >>= 1) {
        s  += __shfl_down(s, off, 64);
        s2 += __shfl_down(s2, off, 64);
    }
    __shared__ float r0[4], r1[4];
    int wv = threadIdx.x >> 6;
    if ((threadIdx.x & 63) == 0) { r0[wv] = s; r1[wv] = s2; }
    __syncthreads();
    if (threadIdx.x == 0) {
        ps[blockIdx.x]       = r0[0] + r0[1] + r0[2] + r0[3];
        ps[512 + blockIdx.x] = r1[0] + r1[1] + r1[2] + r1[3];
    }
}

__global__ void k_stats2f(const float* __restrict__ ps, const float* __restrict__ gamma,
                          const float* __restrict__ beta, float* __restrict__ ab) {
    int o = threadIdx.x;
    float S = 0.f, S2 = 0.f;
#pragma unroll
    for (int sl = 0; sl < 8; ++sl) {
        S  += ps[sl * 64 + o];
        S2 += ps[512 + sl * 64 + o];
    }
    float mean = S / (float)N_PTS;
    float var  = S2 / (float)N_PTS - mean * mean;
    float a = gamma[o] * rsqrtf(var + BN_EPS);
    float b = beta[o] - mean * a;
    ab[o]      = a;
    ab[64 + o] = b;
}

extern "C" void kernel_launch(void* const* d_in, const int* in_sizes, int n_in,
                              void* d_out, int out_size, void* d_ws, size_t ws_size,
                              hipStream_t stream) {
    const float* x   = (const float*)d_in[0];
    const int*   nb  = (const int*)d_in[1];     // int64 in ref -> int32 on device
    const float* w   = (const float*)d_in[2];
    const float* gam = (const float*)d_in[3];
    const float* bet = (const float*)d_in[4];
    float* out = (float*)d_out;
    char* ws = (char*)d_ws;

    if (ws_size >= M_WS_NEED) {
        unsigned short* wt = (unsigned short*)(ws + M_WT_OFF);
        float*          ab = (float*)(ws + M_AB_OFF);
        float*          ps = (float*)(ws + M_PS_OFF);
        unsigned short* xt = (unsigned short*)(ws + M_XT_OFF);
        int*            nt = (int*)(ws + M_NT_OFF);

        k_prep<<<1006, 256, 0, stream>>>(x, nb, w, xt, nt, wt);
        k_conv_mfma<<<CBLK, 256, 0, stream>>>(xt, nt, wt, out, ps);
        k_stats2<<<C_OUT, 256, 0, stream>>>(ps, gam, bet, ab);
        k_norm<<<((C_OUT * N_PTS) / 4 + 255) / 256, 256, 0, stream>>>(out, ab);
    } else {
        float* wtk  = (float*)(ws + F_WTK_OFF);
        float* ab   = (float*)(ws + F_AB_OFF);
        float* ps   = (float*)(ws + F_PS_OFF);
        k_wt_f32<<<(K_NB * C_IN * C_OUT + 255) / 256, 256, 0, stream>>>(w, wtk);
        k_conv_f32<<<N_PTS / 64, 256, 0, stream>>>(x, nb, wtk, out);
        k_stats1<<<512, 256, 0, stream>>>(out, ps);
        k_stats2f<<<1, 64, 0, stream>>>(ps, gam, bet, ab);
        k_norm<<<((C_OUT * N_PTS) / 4 + 255) / 256, 256, 0, stream>>>(out, ab);
    }
}

// Round 6
// 133.330 us; speedup vs baseline: 1.2260x; 1.0080x over previous
//
#include <hip/hip_runtime.h>

#define N_PTS 200000
#define C_IN  32
#define C_OUT 64
#define K_NB  27
#define BN_EPS 1e-5f
#define CBLK  1563     // conv grid: 128 points per block (32 per wave)

using bf16x8 = __attribute__((ext_vector_type(8))) short;
using f32x4  = __attribute__((ext_vector_type(4))) float;

// ---------------- ws layout (MFMA path) ----------------
//  [0, 114688)          wt : bf16[28][64][32]   (row 27 zeros)
//  [114688, 115200)     ab : float[128]
//  [115200, 915456)     ps : float[1563][128]   (per-block partial BN sums)
//  [1048576, +12.8MB)   xt : bf16[N+1][32]      (row N = zeros)
//  [13848640, +22.4MB)  nt : int32[28][N]       (invalid -> N; row 27 = N)
#define M_WT_OFF  0
#define M_AB_OFF  114688
#define M_PS_OFF  115200
#define M_XT_OFF  1048576
#define M_NT_OFF  (1048576 + 12800064)
#define M_WS_NEED ((size_t)M_NT_OFF + 28ull * N_PTS * 4ull)

// ---------------- ws layout (fallback f32 path) ----------------
#define F_WTK_OFF 0
#define F_AB_OFF  221184
#define F_PS_OFF  221824

__device__ __forceinline__ unsigned short f2bf(float f) {
    unsigned int u = __float_as_uint(f);
    u = (u + 0x7fffu + ((u >> 16) & 1u)) >> 16;
    return (unsigned short)u;
}

// ---------- fused prep: blocks [0,782): x->xt bf16 + neigh->nt ; [782,1006): w->wt ----------
__global__ void k_prep(const float* __restrict__ x, const int* __restrict__ neigh,
                       const float* __restrict__ w,
                       unsigned short* __restrict__ xt, int* __restrict__ nt,
                       unsigned short* __restrict__ wt) {
    if (blockIdx.x < 782) {
        int n = blockIdx.x * 256 + threadIdx.x;
        if (n > N_PTS) return;
        unsigned short row[C_IN];
        if (n == N_PTS) {
#pragma unroll
            for (int c = 0; c < C_IN; ++c) row[c] = 0;
        } else {
#pragma unroll
            for (int c = 0; c < C_IN; ++c) row[c] = f2bf(x[(long long)c * N_PTS + n]);
        }
        uint4* dst = (uint4*)(xt + (long long)n * C_IN);
#pragma unroll
        for (int q = 0; q < 4; ++q) dst[q] = ((const uint4*)row)[q];

        if (n < N_PTS) {
#pragma unroll
            for (int k = 0; k < K_NB; ++k) {
                int t = neigh[n * K_NB + k];
                nt[k * N_PTS + n] = (t >= 0 && t < N_PTS) ? t : N_PTS;
            }
            nt[27 * N_PTS + n] = N_PTS;   // pad row for clamped prefetch
        }
    } else {
        int i = (blockIdx.x - 782) * 256 + threadIdx.x;
        if (i >= 28 * C_OUT * C_IN) return;
        int c = i & 31, o = (i >> 5) & 63, k = i >> 11;
        wt[i] = (k < K_NB) ? f2bf(w[(o * C_IN + c) * K_NB + k]) : (unsigned short)0;
    }
}

// ---------- conv via MFMA: 32 pts/wave, B 4-deep gather pipeline, fused BN partials ----------
__launch_bounds__(256, 4)
__global__ void k_conv_mfma(const unsigned short* __restrict__ xt,
                            const int* __restrict__ nt,
                            const unsigned short* __restrict__ wt,
                            float* __restrict__ out,
                            float* __restrict__ ps) {
    __shared__ float sred[512];
    const int lane = threadIdx.x & 63;
    const int wv   = threadIdx.x >> 6;
    const int n0   = blockIdx.x * 128 + wv * 32;
    const int l15  = lane & 15, lq = lane >> 4;
    const bool active = (n0 < N_PTS);

    if (active) {
        const unsigned short* xt_q = xt + lq * 8;               // + t*32
        const unsigned short* wt_q = wt + l15 * C_IN + lq * 8;  // + k*2048 + ot*512
        const int nb = n0 + l15;

        f32x4 acc[2][4];
#pragma unroll
        for (int g = 0; g < 2; ++g)
#pragma unroll
            for (int ot = 0; ot < 4; ++ot) acc[g][ot] = f32x4{0.f, 0.f, 0.f, 0.f};

        // pipeline state: Bq0..Bq3 = gathered rows for k, k+1, k+2, k+3
        //                 ta = idx for gather issued this iter (k+4), tb = next (k+5)
        int ta[2], tb[2];
        bf16x8 Bq0[2], Bq1[2], Bq2[2], Bq3[2], An[4];
        {
            int i0[2], i1[2], i2[2], i3[2];
#pragma unroll
            for (int g = 0; g < 2; ++g) {
                i0[g] = nt[0 * N_PTS + nb + 16 * g];
                i1[g] = nt[1 * N_PTS + nb + 16 * g];
                i2[g] = nt[2 * N_PTS + nb + 16 * g];
                i3[g] = nt[3 * N_PTS + nb + 16 * g];
                ta[g] = nt[4 * N_PTS + nb + 16 * g];
                tb[g] = nt[5 * N_PTS + nb + 16 * g];
            }
#pragma unroll
            for (int g = 0; g < 2; ++g) {
                Bq0[g] = *(const bf16x8*)(xt_q + (long long)i0[g] * C_IN);
                Bq1[g] = *(const bf16x8*)(xt_q + (long long)i1[g] * C_IN);
                Bq2[g] = *(const bf16x8*)(xt_q + (long long)i2[g] * C_IN);
                Bq3[g] = *(const bf16x8*)(xt_q + (long long)i3[g] * C_IN);
            }
#pragma unroll
            for (int ot = 0; ot < 4; ++ot)
                An[ot] = *(const bf16x8*)(wt_q + ot * 512);
        }

        for (int k = 0; k < K_NB; ++k) {
            bf16x8 Ac[4];
#pragma unroll
            for (int ot = 0; ot < 4; ++ot) Ac[ot] = An[ot];
            // issue next-iter A FIRST so the A-wait never drains the gather queue
#pragma unroll
            for (int ot = 0; ot < 4; ++ot)
                An[ot] = *(const bf16x8*)(wt_q + (k + 1) * 2048 + ot * 512);  // row 27 = zeros
            // gather rows for k+4 (ta; zero row past the end)
            bf16x8 Bn[2];
#pragma unroll
            for (int g = 0; g < 2; ++g)
                Bn[g] = *(const bf16x8*)(xt_q + (long long)ta[g] * C_IN);
            // index queue: 2 iters of slack
            int krow = k + 6; if (krow > 27) krow = 27;
#pragma unroll
            for (int g = 0; g < 2; ++g) {
                ta[g] = tb[g];
                tb[g] = nt[krow * N_PTS + nb + 16 * g];
            }

#pragma unroll
            for (int g = 0; g < 2; ++g)
#pragma unroll
                for (int ot = 0; ot < 4; ++ot)
                    acc[g][ot] = __builtin_amdgcn_mfma_f32_16x16x32_bf16(Ac[ot], Bq0[g], acc[g][ot], 0, 0, 0);

#pragma unroll
            for (int g = 0; g < 2; ++g) {
                Bq0[g] = Bq1[g]; Bq1[g] = Bq2[g]; Bq2[g] = Bq3[g]; Bq3[g] = Bn[g];
            }
        }

        // raw f32 out: D layout col=l15 (point), row=lq*4+r (channel within 16-tile)
#pragma unroll
        for (int ot = 0; ot < 4; ++ot)
#pragma unroll
            for (int r = 0; r < 4; ++r)
#pragma unroll
                for (int g = 0; g < 2; ++g)
                    out[(ot * 16 + lq * 4 + r) * N_PTS + n0 + 16 * g + l15] = acc[g][ot][r];

        // fused BN partials over this wave's 32 points
        f32x4 s[4], sq[4];
#pragma unroll
        for (int ot = 0; ot < 4; ++ot) {
            s[ot]  = acc[0][ot] + acc[1][ot];
            sq[ot] = acc[0][ot] * acc[0][ot] + acc[1][ot] * acc[1][ot];
        }
#pragma unroll
        for (int d = 1; d < 16; d <<= 1) {
#pragma unroll
            for (int ot = 0; ot < 4; ++ot)
#pragma unroll
                for (int r = 0; r < 4; ++r) {
                    s[ot][r]  += __shfl_xor(s[ot][r], d);
                    sq[ot][r] += __shfl_xor(sq[ot][r], d);
                }
        }
        if (l15 == 0) {
#pragma unroll
            for (int ot = 0; ot < 4; ++ot)
#pragma unroll
                for (int r = 0; r < 4; ++r) {
                    int ch = ot * 16 + lq * 4 + r;
                    sred[wv * 128 + ch]      = s[ot][r];
                    sred[wv * 128 + 64 + ch] = sq[ot][r];
                }
        }
    } else {
        if (l15 == 0) {
#pragma unroll
            for (int ot = 0; ot < 4; ++ot)
#pragma unroll
                for (int r = 0; r < 4; ++r) {
                    int ch = ot * 16 + lq * 4 + r;
                    sred[wv * 128 + ch]      = 0.f;
                    sred[wv * 128 + 64 + ch] = 0.f;
                }
        }
    }
    __syncthreads();
    if (threadIdx.x < 128) {
        float v = sred[threadIdx.x] + sred[128 + threadIdx.x] +
                  sred[256 + threadIdx.x] + sred[384 + threadIdx.x];
        ps[blockIdx.x * 128 + threadIdx.x] = v;
    }
}

// ---------- reduce per-block partials -> a,b ----------
__global__ void k_stats2(const float* __restrict__ ps, const float* __restrict__ gamma,
                         const float* __restrict__ beta, float* __restrict__ ab) {
    int ch = blockIdx.x;   // 64 blocks
    float s = 0.f, s2 = 0.f;
    for (int b = threadIdx.x; b < CBLK; b += 256) {
        s  += ps[b * 128 + ch];
        s2 += ps[b * 128 + 64 + ch];
    }
#pragma unroll
    for (int off = 32; off > 0; off >>= 1) {
        s  += __shfl_down(s, off, 64);
        s2 += __shfl_down(s2, off, 64);
    }
    __shared__ float r0[4], r1[4];
    int wv = threadIdx.x >> 6;
    if ((threadIdx.x & 63) == 0) { r0[wv] = s; r1[wv] = s2; }
    __syncthreads();
    if (threadIdx.x == 0) {
        float S  = r0[0] + r0[1] + r0[2] + r0[3];
        float S2 = r1[0] + r1[1] + r1[2] + r1[3];
        float mean = S / (float)N_PTS;
        float var  = S2 / (float)N_PTS - mean * mean;
        float a = gamma[ch] * rsqrtf(var + BN_EPS);
        float b = beta[ch] - mean * a;
        ab[ch]      = a;
        ab[64 + ch] = b;
    }
}

// ---------- normalize + relu, in place on d_out ----------
__global__ void k_norm(float* __restrict__ out, const float* __restrict__ ab) {
    int i = blockIdx.x * 256 + threadIdx.x;
    const int total4 = (C_OUT * N_PTS) / 4;
    if (i >= total4) return;
    int o = (i * 4) / N_PTS;
    float a = ab[o], b = ab[64 + o];
    float4 v = ((float4*)out)[i];
    v.x = fmaxf(fmaf(v.x, a, b), 0.f);
    v.y = fmaxf(fmaf(v.y, a, b), 0.f);
    v.z = fmaxf(fmaf(v.z, a, b), 0.f);
    v.w = fmaxf(fmaf(v.w, a, b), 0.f);
    ((float4*)out)[i] = v;
}

// ================= fallback f32 path (small ws) =================
__global__ void k_wt_f32(const float* __restrict__ w, float* __restrict__ wtk) {
    int i = blockIdx.x * 256 + threadIdx.x;
    if (i >= K_NB * C_IN * C_OUT) return;
    int o = i & 63, r = i >> 6, c = r & 31, k = r >> 5;
    wtk[i] = w[(o * C_IN + c) * K_NB + k];
}

__launch_bounds__(256, 1)
__global__ void k_conv_f32(const float* __restrict__ src, const int* __restrict__ neigh,
                           const float* __restrict__ wtk, float* __restrict__ out) {
    __shared__ float wt_s[C_IN * C_OUT];
    const int lane = threadIdx.x & 63;
    const int wave = threadIdx.x >> 6;
    const int n0   = blockIdx.x * 64 + wave * 16;
    float acc[16];
#pragma unroll
    for (int p = 0; p < 16; ++p) acc[p] = 0.f;
    for (int k = 0; k < K_NB; ++k) {
        __syncthreads();
#pragma unroll
        for (int j = 0; j < 8; ++j)
            wt_s[threadIdx.x + j * 256] = wtk[k * (C_IN * C_OUT) + threadIdx.x + j * 256];
        __syncthreads();
        int t[16];
#pragma unroll
        for (int p = 0; p < 16; ++p) t[p] = neigh[(n0 + p) * K_NB + k];
#pragma unroll
        for (int c = 0; c < C_IN; ++c) {
            float wv = wt_s[c * C_OUT + lane];
#pragma unroll
            for (int p = 0; p < 16; ++p) {
                float xv = (t[p] >= 0) ? src[(long long)c * N_PTS + t[p]] : 0.f;
                acc[p] = fmaf(wv, xv, acc[p]);
            }
        }
    }
    float4* dst = (float4*)(out + (long long)lane * N_PTS + n0);
#pragma unroll
    for (int q = 0; q < 4; ++q) dst[q] = ((const float4*)acc)[q];
}

__global__ void k_stats1(const float* __restrict__ raw, float* __restrict__ ps) {
    int o = blockIdx.x & 63, sl = blockIdx.x >> 6;
    const int per = N_PTS / 8;
    const float4* row = (const float4*)(raw + (long long)o * N_PTS + (long long)sl * per);
    float s = 0.f, s2 = 0.f;
    for (int i = threadIdx.x; i < per / 4; i += 256) {
        float4 v = row[i];
        s  += v.x + v.y + v.z + v.w;
        s2 += v.x * v.x + v.y * v.y + v.z * v.z + v.w * v.w;
    }
#pragma unroll
    for (int off = 32; off > 0; off >>= 1) {
        s  += __shfl_down(s, off, 64);
        s2 += __shfl_down(s2, off, 64);
    }
    __shared__ float r0[4], r1[4];
    int wv = threadIdx.x >> 6;
    if ((threadIdx.x & 63) == 0) { r0[wv] = s; r1[wv] = s2; }
    __syncthreads();
    if (threadIdx.x == 0) {
        ps[blockIdx.x]       = r0[0] + r0[1] + r0[2] + r0[3];
        ps[512 + blockIdx.x] = r1[0] + r1[1] + r1[2] + r1[3];
    }
}

__global__ void k_stats2f(const float* __restrict__ ps, const float* __restrict__ gamma,
                          const float* __restrict__ beta, float* __restrict__ ab) {
    int o = threadIdx.x;
    float S = 0.f, S2 = 0.f;
#pragma unroll
    for (int sl = 0; sl < 8; ++sl) {
        S  += ps[sl * 64 + o];
        S2 += ps[512 + sl * 64 + o];
    }
    float mean = S / (float)N_PTS;
    float var  = S2 / (float)N_PTS - mean * mean;
    float a = gamma[o] * rsqrtf(var + BN_EPS);
    float b = beta[o] - mean * a;
    ab[o]      = a;
    ab[64 + o] = b;
}

extern "C" void kernel_launch(void* const* d_in, const int* in_sizes, int n_in,
                              void* d_out, int out_size, void* d_ws, size_t ws_size,
                              hipStream_t stream) {
    const float* x   = (const float*)d_in[0];
    const int*   nb  = (const int*)d_in[1];     // int64 in ref -> int32 on device
    const float* w   = (const float*)d_in[2];
    const float* gam = (const float*)d_in[3];
    const float* bet = (const float*)d_in[4];
    float* out = (float*)d_out;
    char* ws = (char*)d_ws;

    if (ws_size >= M_WS_NEED) {
        unsigned short* wt = (unsigned short*)(ws + M_WT_OFF);
        float*          ab = (float*)(ws + M_AB_OFF);
        float*          ps = (float*)(ws + M_PS_OFF);
        unsigned short* xt = (unsigned short*)(ws + M_XT_OFF);
        int*            nt = (int*)(ws + M_NT_OFF);

        k_prep<<<1006, 256, 0, stream>>>(x, nb, w, xt, nt, wt);
        k_conv_mfma<<<CBLK, 256, 0, stream>>>(xt, nt, wt, out, ps);
        k_stats2<<<C_OUT, 256, 0, stream>>>(ps, gam, bet, ab);
        k_norm<<<((C_OUT * N_PTS) / 4 + 255) / 256, 256, 0, stream>>>(out, ab);
    } else {
        float* wtk  = (float*)(ws + F_WTK_OFF);
        float* ab   = (float*)(ws + F_AB_OFF);
        float* ps   = (float*)(ws + F_PS_OFF);
        k_wt_f32<<<(K_NB * C_IN * C_OUT + 255) / 256, 256, 0, stream>>>(w, wtk);
        k_conv_f32<<<N_PTS / 64, 256, 0, stream>>>(x, nb, wtk, out);
        k_stats1<<<512, 256, 0, stream>>>(out, ps);
        k_stats2f<<<1, 64, 0, stream>>>(ps, gam, bet, ab);
        k_norm<<<((C_OUT * N_PTS) / 4 + 255) / 256, 256, 0, stream>>>(out, ab);
    }
}

// Round 7
// 127.692 us; speedup vs baseline: 1.2801x; 1.0442x over previous
//
#include <hip/hip_runtime.h>

#define N_PTS 200000
#define C_IN  32
#define C_OUT 64
#define K_NB  27
#define BN_EPS 1e-5f
#define CBLK  3125     // conv grid: 64 points per block

using bf16x8 = __attribute__((ext_vector_type(8))) short;
using f32x4  = __attribute__((ext_vector_type(4))) float;

typedef const __attribute__((address_space(1))) char GP;
typedef __attribute__((address_space(3))) char LP;

// ---------------- ws layout (MFMA path) ----------------
//  [0, 114688)           wt : bf16[28][64][32]  (row 27 zeros)
//  [114688, 115200)      ab : float[128]
//  [131072, +1.6MB)      ps : float[3125][128]  (per-block partial BN sums)
//  [2097152, +12.8MB)    xt : bf16[N+1][32]     (row N = zeros)
#define M_WT_OFF  0
#define M_AB_OFF  114688
#define M_PS_OFF  131072
#define M_XT_OFF  2097152
#define M_WS_NEED ((size_t)M_XT_OFF + (size_t)(N_PTS + 1) * C_IN * 2)

// ---------------- ws layout (fallback f32 path) ----------------
#define F_WTK_OFF 0
#define F_AB_OFF  221184
#define F_PS_OFF  221824

__device__ __forceinline__ unsigned short f2bf(float f) {
    unsigned int u = __float_as_uint(f);
    u = (u + 0x7fffu + ((u >> 16) & 1u)) >> 16;
    return (unsigned short)u;
}

// ---------- prep: blocks [0,782): x->xt bf16 (+zero row); [782,1006): w->wt ----------
__global__ void k_prep(const float* __restrict__ x, const float* __restrict__ w,
                       unsigned short* __restrict__ xt, unsigned short* __restrict__ wt) {
    if (blockIdx.x < 782) {
        int n = blockIdx.x * 256 + threadIdx.x;
        if (n > N_PTS) return;
        unsigned short row[C_IN];
        if (n == N_PTS) {
#pragma unroll
            for (int c = 0; c < C_IN; ++c) row[c] = 0;
        } else {
#pragma unroll
            for (int c = 0; c < C_IN; ++c) row[c] = f2bf(x[(long long)c * N_PTS + n]);
        }
        uint4* dst = (uint4*)(xt + (long long)n * C_IN);
#pragma unroll
        for (int q = 0; q < 4; ++q) dst[q] = ((const uint4*)row)[q];
    } else {
        int i = (blockIdx.x - 782) * 256 + threadIdx.x;
        if (i >= 28 * C_OUT * C_IN) return;
        int c = i & 31, o = (i >> 5) & 63, k = i >> 11;
        wt[i] = (k < K_NB) ? f2bf(w[(o * C_IN + c) * K_NB + k]) : (unsigned short)0;
    }
}

// ---------- conv: 64 pts/block, och-split waves, LDS B-ring, asm counted-vmcnt pipeline ----------
// LDS: bufB[6][4KB] ring (slot s holds, per g-group, [q][r] 16B cells) + ntb[27][64] ints
__launch_bounds__(256, 5)
__global__ void k_conv_mfma(const unsigned short* __restrict__ xt,
                            const int* __restrict__ neigh,
                            const unsigned short* __restrict__ wt,
                            float* __restrict__ out,
                            float* __restrict__ ps) {
    __shared__ __align__(16) char lds_raw[6 * 4096 + K_NB * 64 * 4];
    char* bufB = lds_raw;
    int*  ntb  = (int*)(lds_raw + 24576);

    const int lane = threadIdx.x & 63;
    const int w    = threadIdx.x >> 6;          // wave id = och-quarter = staging g-group
    const int l15  = lane & 15, lq = lane >> 4;
    const int n0   = blockIdx.x * 64;

    // ---- preload this block's neighbor indices into LDS (validity-remapped) ----
    {
        int p  = threadIdx.x & 63;
        int kb = (threadIdx.x >> 6) * 7;        // 0,7,14,21
        const int* nrow = neigh + (long long)(n0 + p) * K_NB;
#pragma unroll
        for (int i = 0; i < 7; ++i) {
            int kk = kb + i;
            if (kk < K_NB) {
                int t = nrow[kk];
                ntb[kk * 64 + p] = ((unsigned)t < N_PTS) ? t : N_PTS;
            }
        }
    }
    __syncthreads();

    const char* xtb = (const char*)xt;                              // 64B rows
    const unsigned short* wtA = wt + w * 512 + l15 * 32 + lq * 8;   // + k*2048
    const unsigned qoff = (unsigned)(lq * 16);

    unsigned bufB_a = (unsigned)(unsigned long long)(LP*)lds_raw;
    unsigned ntb_a  = bufB_a + 24576;
    unsigned badr   = bufB_a + (unsigned)(lq * 256 + l15 * 16);     // + slot*4096 + g*1024 (imm)
    unsigned tadr   = ntb_a + (unsigned)(w * 64 + l15 * 4);         // + k*256 (imm)

    f32x4 acc0 = {0.f,0.f,0.f,0.f}, acc1 = {0.f,0.f,0.f,0.f},
          acc2 = {0.f,0.f,0.f,0.f}, acc3 = {0.f,0.f,0.f,0.f};
    bf16x8 Ar[4];
    int tcur;

    // ---- prologue: stage k=0..3 + A(0..3); leave t(4) pending ----
#define PSTEP(KK) \
    asm volatile("ds_read_b32 %0, %1 offset:%2" : "=v"(tcur) : "v"(tadr), "i"((KK)*256)); \
    asm volatile("s_waitcnt lgkmcnt(0)" ::: "memory"); \
    __builtin_amdgcn_sched_barrier(0); \
    __builtin_amdgcn_global_load_lds((GP*)(xtb + (unsigned long long)(unsigned)tcur * 64ull + qoff), \
        (LP*)(bufB + (KK)*4096 + w*1024), 16, 0, 0); \
    asm volatile("global_load_dwordx4 %0, %1, off" : "=v"(Ar[(KK)&3]) : "v"(wtA + (KK)*2048)); \
    __builtin_amdgcn_sched_barrier(0);

    PSTEP(0) PSTEP(1) PSTEP(2) PSTEP(3)
#undef PSTEP
    asm volatile("ds_read_b32 %0, %1 offset:%2" : "=v"(tcur) : "v"(tadr), "i"(4*256));

    // ---- main loop, fully unrolled; 2 VMEM/iter, vmcnt counted, raw barrier ----
#define STEP(K, VM, PF, NT, LG) { \
    if (PF) { \
        asm volatile("s_waitcnt lgkmcnt(0)" ::: "memory"); \
        __builtin_amdgcn_sched_barrier(0); \
        __builtin_amdgcn_global_load_lds((GP*)(xtb + (unsigned long long)(unsigned)tcur * 64ull + qoff), \
            (LP*)(bufB + (((K)+4)%6)*4096 + w*1024), 16, 0, 0); \
    } \
    __builtin_amdgcn_sched_barrier(0); \
    asm volatile("s_waitcnt vmcnt(%0)" :: "i"(VM) : "memory"); \
    __builtin_amdgcn_sched_barrier(0); \
    asm volatile("s_barrier" ::: "memory"); \
    __builtin_amdgcn_sched_barrier(0); \
    bf16x8 b0, b1, b2, b3; \
    asm volatile("ds_read_b128 %0, %1 offset:%2" : "=v"(b0) : "v"(badr), "i"(((K)%6)*4096 + 0)); \
    asm volatile("ds_read_b128 %0, %1 offset:%2" : "=v"(b1) : "v"(badr), "i"(((K)%6)*4096 + 1024)); \
    asm volatile("ds_read_b128 %0, %1 offset:%2" : "=v"(b2) : "v"(badr), "i"(((K)%6)*4096 + 2048)); \
    asm volatile("ds_read_b128 %0, %1 offset:%2" : "=v"(b3) : "v"(badr), "i"(((K)%6)*4096 + 3072)); \
    if (NT) { asm volatile("ds_read_b32 %0, %1 offset:%2" : "=v"(tcur) : "v"(tadr), "i"(((K)+5)*256)); } \
    asm volatile("s_waitcnt lgkmcnt(%0)" :: "i"(LG) : "memory"); \
    __builtin_amdgcn_sched_barrier(0); \
    acc0 = __builtin_amdgcn_mfma_f32_16x16x32_bf16(Ar[(K)&3], b0, acc0, 0, 0, 0); \
    acc1 = __builtin_amdgcn_mfma_f32_16x16x32_bf16(Ar[(K)&3], b1, acc1, 0, 0, 0); \
    acc2 = __builtin_amdgcn_mfma_f32_16x16x32_bf16(Ar[(K)&3], b2, acc2, 0, 0, 0); \
    acc3 = __builtin_amdgcn_mfma_f32_16x16x32_bf16(Ar[(K)&3], b3, acc3, 0, 0, 0); \
    if (PF) { \
        asm volatile("global_load_dwordx4 %0, %1, off" : "=v"(Ar[((K)+4)&3]) : "v"(wtA + ((K)+4)*2048)); \
    } \
    __builtin_amdgcn_sched_barrier(0); \
}

    STEP(0,7,1,1,1)  STEP(1,7,1,1,1)  STEP(2,7,1,1,1)  STEP(3,7,1,1,1)
    STEP(4,7,1,1,1)  STEP(5,7,1,1,1)  STEP(6,7,1,1,1)  STEP(7,7,1,1,1)
    STEP(8,7,1,1,1)  STEP(9,7,1,1,1)  STEP(10,7,1,1,1) STEP(11,7,1,1,1)
    STEP(12,7,1,1,1) STEP(13,7,1,1,1) STEP(14,7,1,1,1) STEP(15,7,1,1,1)
    STEP(16,7,1,1,1) STEP(17,7,1,1,1) STEP(18,7,1,1,1) STEP(19,7,1,1,1)
    STEP(20,7,1,1,1) STEP(21,7,1,1,1) STEP(22,7,1,0,0)
    STEP(23,6,0,0,0) STEP(24,4,0,0,0) STEP(25,2,0,0,0) STEP(26,0,0,0,0)
#undef STEP

    asm volatile("s_waitcnt vmcnt(0) lgkmcnt(0)" ::: "memory");
    __builtin_amdgcn_sched_barrier(0);

    // ---- out writes: och = 16w + lq*4 + r, point = n0 + g*16 + l15 ----
#pragma unroll
    for (int r = 0; r < 4; ++r) {
        float* o = out + (long long)(16 * w + lq * 4 + r) * N_PTS + n0 + l15;
        o[0]  = acc0[r];
        o[16] = acc1[r];
        o[32] = acc2[r];
        o[48] = acc3[r];
    }

    // ---- fused BN partials: sum over this block's 64 points per och ----
    f32x4 s  = acc0 + acc1 + acc2 + acc3;
    f32x4 sq = acc0 * acc0 + acc1 * acc1 + acc2 * acc2 + acc3 * acc3;
#pragma unroll
    for (int d = 1; d < 16; d <<= 1) {
#pragma unroll
        for (int r = 0; r < 4; ++r) {
            s[r]  += __shfl_xor(s[r], d);
            sq[r] += __shfl_xor(sq[r], d);
        }
    }
    if (l15 == 0) {
#pragma unroll
        for (int r = 0; r < 4; ++r) {
            int ch = 16 * w + lq * 4 + r;
            ps[blockIdx.x * 128 + ch]      = s[r];
            ps[blockIdx.x * 128 + 64 + ch] = sq[r];
        }
    }
}

// ---------- reduce per-block partials -> a,b ----------
__global__ void k_stats2(const float* __restrict__ ps, const float* __restrict__ gamma,
                         const float* __restrict__ beta, float* __restrict__ ab) {
    int ch = blockIdx.x;   // 64 blocks
    float s = 0.f, s2 = 0.f;
    for (int b = threadIdx.x; b < CBLK; b += 256) {
        s  += ps[b * 128 + ch];
        s2 += ps[b * 128 + 64 + ch];
    }
#pragma unroll
    for (int off = 32; off > 0; off >>= 1) {
        s  += __shfl_down(s, off, 64);
        s2 += __shfl_down(s2, off, 64);
    }
    __shared__ float r0[4], r1[4];
    int wv = threadIdx.x >> 6;
    if ((threadIdx.x & 63) == 0) { r0[wv] = s; r1[wv] = s2; }
    __syncthreads();
    if (threadIdx.x == 0) {
        float S  = r0[0] + r0[1] + r0[2] + r0[3];
        float S2 = r1[0] + r1[1] + r1[2] + r1[3];
        float mean = S / (float)N_PTS;
        float var  = S2 / (float)N_PTS - mean * mean;
        float a = gamma[ch] * rsqrtf(var + BN_EPS);
        float b = beta[ch] - mean * a;
        ab[ch]      = a;
        ab[64 + ch] = b;
    }
}

// ---------- normalize + relu, in place on d_out ----------
__global__ void k_norm(float* __restrict__ out, const float* __restrict__ ab) {
    int i = blockIdx.x * 256 + threadIdx.x;
    const int total4 = (C_OUT * N_PTS) / 4;
    if (i >= total4) return;
    int o = (i * 4) / N_PTS;
    float a = ab[o], b = ab[64 + o];
    float4 v = ((float4*)out)[i];
    v.x = fmaxf(fmaf(v.x, a, b), 0.f);
    v.y = fmaxf(fmaf(v.y, a, b), 0.f);
    v.z = fmaxf(fmaf(v.z, a, b), 0.f);
    v.w = fmaxf(fmaf(v.w, a, b), 0.f);
    ((float4*)out)[i] = v;
}

// ================= fallback f32 path (small ws) =================
__global__ void k_wt_f32(const float* __restrict__ w, float* __restrict__ wtk) {
    int i = blockIdx.x * 256 + threadIdx.x;
    if (i >= K_NB * C_IN * C_OUT) return;
    int o = i & 63, r = i >> 6, c = r & 31, k = r >> 5;
    wtk[i] = w[(o * C_IN + c) * K_NB + k];
}

__launch_bounds__(256, 1)
__global__ void k_conv_f32(const float* __restrict__ src, const int* __restrict__ neigh,
                           const float* __restrict__ wtk, float* __restrict__ out) {
    __shared__ float wt_s[C_IN * C_OUT];
    const int lane = threadIdx.x & 63;
    const int wave = threadIdx.x >> 6;
    const int n0   = blockIdx.x * 64 + wave * 16;
    float acc[16];
#pragma unroll
    for (int p = 0; p < 16; ++p) acc[p] = 0.f;
    for (int k = 0; k < K_NB; ++k) {
        __syncthreads();
#pragma unroll
        for (int j = 0; j < 8; ++j)
            wt_s[threadIdx.x + j * 256] = wtk[k * (C_IN * C_OUT) + threadIdx.x + j * 256];
        __syncthreads();
        int t[16];
#pragma unroll
        for (int p = 0; p < 16; ++p) t[p] = neigh[(n0 + p) * K_NB + k];
#pragma unroll
        for (int c = 0; c < C_IN; ++c) {
            float wv = wt_s[c * C_OUT + lane];
#pragma unroll
            for (int p = 0; p < 16; ++p) {
                float xv = (t[p] >= 0) ? src[(long long)c * N_PTS + t[p]] : 0.f;
                acc[p] = fmaf(wv, xv, acc[p]);
            }
        }
    }
    float4* dst = (float4*)(out + (long long)lane * N_PTS + n0);
#pragma unroll
    for (int q = 0; q < 4; ++q) dst[q] = ((const float4*)acc)[q];
}

__global__ void k_stats1(const float* __restrict__ raw, float* __restrict__ ps) {
    int o = blockIdx.x & 63, sl = blockIdx.x >> 6;
    const int per = N_PTS / 8;
    const float4* row = (const float4*)(raw + (long long)o * N_PTS + (long long)sl * per);
    float s = 0.f, s2 = 0.f;
    for (int i = threadIdx.x; i < per / 4; i += 256) {
        float4 v = row[i];
        s  += v.x + v.y + v.z + v.w;
        s2 += v.x * v.x + v.y * v.y + v.z * v.z + v.w * v.w;
    }
#pragma unroll
    for (int off = 32; off > 0; off >>= 1) {
        s  += __shfl_down(s, off, 64);
        s2 += __shfl_down(s2, off, 64);
    }
    __shared__ float r0[4], r1[4];
    int wv = threadIdx.x >> 6;
    if ((threadIdx.x & 63) == 0) { r0[wv] = s; r1[wv] = s2; }
    __syncthreads();
    if (threadIdx.x == 0) {
        ps[blockIdx.x]       = r0[0] + r0[1] + r0[2] + r0[3];
        ps[512 + blockIdx.x] = r1[0] + r1[1] + r1[2] + r1[3];
    }
}

__global__ void k_stats2f(const float* __restrict__ ps, const float* __restrict__ gamma,
                          const float* __restrict__ beta, float* __restrict__ ab) {
    int o = threadIdx.x;
    float S = 0.f, S2 = 0.f;
#pragma unroll
    for (int sl = 0; sl < 8; ++sl) {
        S  += ps[sl * 64 + o];
        S2 += ps[512 + sl * 64 + o];
    }
    float mean = S / (float)N_PTS;
    float var  = S2 / (float)N_PTS - mean * mean;
    float a = gamma[o] * rsqrtf(var + BN_EPS);
    float b = beta[o] - mean * a;
    ab[o]      = a;
    ab[64 + o] = b;
}

extern "C" void kernel_launch(void* const* d_in, const int* in_sizes, int n_in,
                              void* d_out, int out_size, void* d_ws, size_t ws_size,
                              hipStream_t stream) {
    const float* x   = (const float*)d_in[0];
    const int*   nb  = (const int*)d_in[1];     // int64 in ref -> int32 on device
    const float* w   = (const float*)d_in[2];
    const float* gam = (const float*)d_in[3];
    const float* bet = (const float*)d_in[4];
    float* out = (float*)d_out;
    char* ws = (char*)d_ws;

    if (ws_size >= M_WS_NEED) {
        unsigned short* wt = (unsigned short*)(ws + M_WT_OFF);
        float*          ab = (float*)(ws + M_AB_OFF);
        float*          ps = (float*)(ws + M_PS_OFF);
        unsigned short* xt = (unsigned short*)(ws + M_XT_OFF);

        k_prep<<<1006, 256, 0, stream>>>(x, w, xt, wt);
        k_conv_mfma<<<CBLK, 256, 0, stream>>>(xt, nb, wt, out, ps);
        k_stats2<<<C_OUT, 256, 0, stream>>>(ps, gam, bet, ab);
        k_norm<<<((C_OUT * N_PTS) / 4 + 255) / 256, 256, 0, stream>>>(out, ab);
    } else {
        float* wtk  = (float*)(ws + F_WTK_OFF);
        float* ab   = (float*)(ws + F_AB_OFF);
        float* ps   = (float*)(ws + F_PS_OFF);
        k_wt_f32<<<(K_NB * C_IN * C_OUT + 255) / 256, 256, 0, stream>>>(w, wtk);
        k_conv_f32<<<N_PTS / 64, 256, 0, stream>>>(x, nb, wtk, out);
        k_stats1<<<512, 256, 0, stream>>>(out, ps);
        k_stats2f<<<1, 64, 0, stream>>>(ps, gam, bet, ab);
        k_norm<<<((C_OUT * N_PTS) / 4 + 255) / 256, 256, 0, stream>>>(out, ab);
    }
}